// Round 2
// 184.753 us; speedup vs baseline: 1.0004x; 1.0004x over previous
//
#include <hip/hip_runtime.h>
#include <stdint.h>

static constexpr int kN   = 50000;   // nodes
static constexpr int kCap = 64;      // adjacency capacity per node (Poisson(12) tail @64 ~ 1e-25)
static constexpr int kW2TBlocks = 16;   // 16*256 = 4096 = W2T dwords
static constexpr int kGemm1Blocks = 1563;

typedef __attribute__((ext_vector_type(8))) _Float16 f16x8;  // MFMA A/B fragment
typedef __attribute__((ext_vector_type(2))) _Float16 f16x2;  // packed pair -> v_pk_add_f16
typedef __attribute__((ext_vector_type(4))) float f32x4;     // MFMA 16x16 accumulator

// ---------------- threefry2x32-20 (verified vs Random123 KAT) ----------------
__device__ __forceinline__ uint32_t rotl32(uint32_t v, uint32_t r) {
  return (v << r) | (v >> (32u - r));
}

__device__ __forceinline__ uint2 threefry2x32(uint32_t k0, uint32_t k1,
                                              uint32_t x0, uint32_t x1) {
  const uint32_t k2 = k0 ^ k1 ^ 0x1BD11BDAu;
  x0 += k0; x1 += k1;
#define TFR(r) { x0 += x1; x1 = rotl32(x1, r); x1 ^= x0; }
  TFR(13u) TFR(15u) TFR(26u) TFR(6u)
  x0 += k1; x1 += k2 + 1u;
  TFR(17u) TFR(29u) TFR(16u) TFR(24u)
  x0 += k2; x1 += k0 + 2u;
  TFR(13u) TFR(15u) TFR(26u) TFR(6u)
  x0 += k0; x1 += k1 + 3u;
  TFR(17u) TFR(29u) TFR(16u) TFR(24u)
  x0 += k1; x1 += k2 + 4u;
  TFR(13u) TFR(15u) TFR(26u) TFR(6u)
  x0 += k2; x1 += k0 + 5u;
#undef TFR
  return make_uint2(x0, x1);
}

__device__ __forceinline__ bool drop_elem(uint32_t j) {
  const uint2 r = threefry2x32(0u, 42u, 0u, j);
  return ((r.x ^ r.y) >> 31) != 0u;
}

// ---------------- f16 pack/unpack ----------------
union PairU { f16x2 h; uint32_t u; };
__device__ __forceinline__ uint32_t pack_f16x2(float lo, float hi) {
  PairU p; p.h[0] = (_Float16)lo; p.h[1] = (_Float16)hi; return p.u;
}
__device__ __forceinline__ float f16_lo(f16x2 v) { return (float)v[0]; }
__device__ __forceinline__ float f16_hi(f16x2 v) { return (float)v[1]; }

union FragU { uint4 q; f16x8 f; };

// ---------------- K1: adj-build | W2T-pack | gemm1 (block-range split) ----------------
// Blocks [0, adjBlocks): adjacency build, 4 edges/thread (independent atomic chains).
// Blocks [adjBlocks, adjBlocks+16): W2T[n*64+i] = pack(W2[2i][n], W2[2i+1][n]).
// Blocks [adjBlocks+16, ...): gemm1 z1h = pack_f16(x @ W1); self-packs W1 into LDS
// (no W1T dependency, so all three regions are fully independent -> overlap).
// Wave = 16 rows x 64 cols: 4 kb x 4 ct MFMAs. A: x converted to f16 in-flight.
// Layouts (HW-verified r8): A[m=lane&15][k=quad*8+j], B[n=lane&15][k=quad*8+j],
// D: col=lane&15, row=quad*4+reg.
__global__ __launch_bounds__(256, 4) void k1_adj_w2t_gemm1(
    const float* __restrict__ x, const float* __restrict__ W1,
    const float* __restrict__ W2, uint32_t* __restrict__ W2T,
    const int* __restrict__ src, const int* __restrict__ dst,
    int* __restrict__ cnt, int* __restrict__ adj, int E, int adjBlocks,
    uint32_t* __restrict__ z1h) {
  __shared__ uint32_t WT[128 * 68];  // 34 KB (gemm1 region only)

  if (blockIdx.x < adjBlocks) {
    const int base = blockIdx.x * 1024 + threadIdx.x;
    int d[4], s[4];
    bool ok[4];
#pragma unroll
    for (int j = 0; j < 4; ++j) {
      const int e = base + j * 256;
      ok[j] = (e < E);
      d[j] = ok[j] ? dst[e] : 0;
      s[j] = ok[j] ? src[e] : 0;
    }
    int slot[4];
#pragma unroll
    for (int j = 0; j < 4; ++j)
      slot[j] = ok[j] ? atomicAdd(&cnt[d[j]], 1) : kCap;
#pragma unroll
    for (int j = 0; j < 4; ++j)
      if (ok[j] && slot[j] < kCap) adj[d[j] * kCap + slot[j]] = s[j];
    return;
  }

  if (blockIdx.x < adjBlocks + kW2TBlocks) {
    const int w = (blockIdx.x - adjBlocks) * 256 + threadIdx.x;  // < 4096
    const int n = w >> 6, i = w & 63;
    W2T[w] = pack_f16x2(W2[(size_t)(2 * i) * 64 + n], W2[(size_t)(2 * i + 1) * 64 + n]);
    return;
  }

  // ---- gemm1 region ----
  // Self-pack W1: WT[n*68+i] = pack(W1[2i][n], W1[2i+1][n]).
  // Consecutive lanes -> consecutive n: coalesced global reads; LDS write
  // 8-way conflict, one-time staging (negligible).
  for (int v = threadIdx.x; v < 128 * 64; v += 256) {
    const int i = v >> 7;   // 0..63
    const int n = v & 127;  // 0..127
    WT[n * 68 + i] = pack_f16x2(W1[(size_t)(2 * i) * 128 + n],
                                W1[(size_t)(2 * i + 1) * 128 + n]);
  }
  __syncthreads();

  const int lane = threadIdx.x & 63;
  const int wid  = threadIdx.x >> 6;
  const int gb   = blockIdx.x - adjBlocks - kW2TBlocks;  // 0..1562
  const int rb   = gb * 2 + (wid >> 1);                  // -> rb 0..3125
  if (rb >= 3125) return;                                // tail wave (after barrier)
  const int cg   = wid & 1;                              // column group: cols cg*64..+63
  const int n0   = rb * 16;
  const int quad = lane >> 4;
  const int mrow = lane & 15;

  const float* xp = x + (size_t)(n0 + mrow) * 128 + quad * 8;
  f32x4 acc[4] = {{0.f,0.f,0.f,0.f},{0.f,0.f,0.f,0.f},{0.f,0.f,0.f,0.f},{0.f,0.f,0.f,0.f}};

#pragma unroll
  for (int kb = 0; kb < 4; ++kb) {
    const float4 lo = *reinterpret_cast<const float4*>(xp + kb * 32);
    const float4 hi = *reinterpret_cast<const float4*>(xp + kb * 32 + 4);
    FragU a;
    a.q = make_uint4(pack_f16x2(lo.x, lo.y), pack_f16x2(lo.z, lo.w),
                     pack_f16x2(hi.x, hi.y), pack_f16x2(hi.z, hi.w));
#pragma unroll
    for (int ct = 0; ct < 4; ++ct) {
      const int n = cg * 64 + ct * 16 + mrow;
      FragU b;
      b.q = *reinterpret_cast<const uint4*>(&WT[n * 68 + kb * 16 + quad * 4]);
      acc[ct] = __builtin_amdgcn_mfma_f32_16x16x32_f16(a.f, b.f, acc[ct], 0, 0, 0);
    }
  }

#pragma unroll
  for (int ct = 0; ct < 4; ++ct) {
#pragma unroll
    for (int r = 0; r < 4; ++r) {
      const float v = acc[ct][r];
      const float vOdd = __shfl(v, lane | 1);
      if ((lane & 1) == 0) {
        const int row = n0 + quad * 4 + r;
        z1h[(size_t)row * 64 + cg * 32 + ct * 8 + (mrow >> 1)] = pack_f16x2(v, vOdd);
      }
    }
  }
}

// ---------------- K2: agg1 + gemm2 fused ----------------
// Agg phase identical to proven agg1 (2 nodes/wave, 16 loads in flight, no LDS
// on the gather path). h rows go to a tiny LDS tile instead of global hh, then
// each wave computes one 16-col tile of z2 = h @ W2 straight out of LDS.
// Eliminates the 12.8 MB hh write + 12.8 MB read + one launch.
__global__ __launch_bounds__(256, 8) void agg1_gemm2(
    const f16x2* __restrict__ z1h, const int* __restrict__ adj,
    const int* __restrict__ cnt, const float* __restrict__ b1,
    const f16x2* __restrict__ zpad, const uint32_t* __restrict__ W2T,
    uint32_t* __restrict__ z2h) {
  __shared__ uint32_t WT[64 * 68];  // 17.4 KB W2 packed
  __shared__ uint32_t HT[8 * 68];   // 2.2 KB h-tile (8 rows/block)

  // Stage W2T linearly (conflict-free); consumed only after the post-agg barrier.
  for (int v = threadIdx.x; v < 64 * 64; v += 256)
    WT[(v >> 6) * 68 + (v & 63)] = W2T[v];

  const int lane = threadIdx.x & 63;
  const int wid  = threadIdx.x >> 6;
  const int n0   = blockIdx.x * 8;       // 6250 blocks * 8 nodes
  const int nA = n0 + 2 * wid, nB = nA + 1;

  const int vaA = adj[(size_t)nA * kCap + lane];
  const int vaB = adj[(size_t)nB * kCap + lane];
  int dA = __builtin_amdgcn_readfirstlane(cnt[nA]); if (dA > kCap) dA = kCap;
  int dB = __builtin_amdgcn_readfirstlane(cnt[nB]); if (dB > kCap) dB = kCap;
  const int dm = (dA > dB) ? dA : dB;

  f16x2 sA0 = z1h[(size_t)nA * 64 + lane];  // self
  f16x2 sB0 = z1h[(size_t)nB * 64 + lane];
  f16x2 sA1 = (f16x2)0, sA2 = (f16x2)0, sA3 = (f16x2)0;
  f16x2 sB1 = (f16x2)0, sB2 = (f16x2)0, sB3 = (f16x2)0;

  int e = 0;
  while (e < dm) {
    f16x2 vA[16], vB[16];
#pragma unroll
    for (int j = 0; j < 16; ++j) {
      const int ee = e + j;
      const int ia = __builtin_amdgcn_readlane(vaA, ee);
      const f16x2* ba = (ee < dA) ? (z1h + (size_t)ia * 64) : zpad;  // scalar select
      vA[j] = ba[lane];
    }
#pragma unroll
    for (int j = 0; j < 16; ++j) {
      const int ee = e + j;
      const int ib = __builtin_amdgcn_readlane(vaB, ee);
      const f16x2* bb = (ee < dB) ? (z1h + (size_t)ib * 64) : zpad;
      vB[j] = bb[lane];
    }
#pragma unroll
    for (int j = 0; j < 16; ++j) {
      if ((j & 3) == 0)      { sA0 += vA[j]; sB0 += vB[j]; }
      else if ((j & 3) == 1) { sA1 += vA[j]; sB1 += vB[j]; }
      else if ((j & 3) == 2) { sA2 += vA[j]; sB2 += vB[j]; }
      else                   { sA3 += vA[j]; sB3 += vB[j]; }
    }
    e += 16;
  }

  const float2 bb = *reinterpret_cast<const float2*>(b1 + 2 * lane);
  {
    const f16x2 s = (sA0 + sA1) + (sA2 + sA3);
    float hx = fmaxf(f16_lo(s) + bb.x, 0.0f);
    float hy = fmaxf(f16_hi(s) + bb.y, 0.0f);
    const uint32_t j0 = (uint32_t)nA * 128u + 2u * (uint32_t)lane;
    hx = drop_elem(j0)      ? 0.0f : hx * 2.0f;
    hy = drop_elem(j0 + 1u) ? 0.0f : hy * 2.0f;
    HT[(2 * wid) * 68 + lane] = pack_f16x2(hx, hy);   // conflict-free row write
  }
  {
    const f16x2 s = (sB0 + sB1) + (sB2 + sB3);
    float hx = fmaxf(f16_lo(s) + bb.x, 0.0f);
    float hy = fmaxf(f16_hi(s) + bb.y, 0.0f);
    const uint32_t j0 = (uint32_t)nB * 128u + 2u * (uint32_t)lane;
    hx = drop_elem(j0)      ? 0.0f : hx * 2.0f;
    hy = drop_elem(j0 + 1u) ? 0.0f : hy * 2.0f;
    HT[(2 * wid + 1) * 68 + lane] = pack_f16x2(hx, hy);
  }
  __syncthreads();

  // ---- gemm2 phase: wave wid computes output cols [wid*16, wid*16+16) for
  // the block's 8 rows. A-fragment rows 8-15 clamped to 0-7 (outputs unwritten).
  const int quad = lane >> 4;
  const int mrow = lane & 15;
  const int ct   = wid;
  f32x4 acc = {0.f, 0.f, 0.f, 0.f};
#pragma unroll
  for (int kb = 0; kb < 4; ++kb) {
    FragU a;
    a.q = *reinterpret_cast<const uint4*>(&HT[(mrow & 7) * 68 + kb * 16 + quad * 4]);
    FragU b;
    b.q = *reinterpret_cast<const uint4*>(&WT[(ct * 16 + mrow) * 68 + kb * 16 + quad * 4]);
    acc = __builtin_amdgcn_mfma_f32_16x16x32_f16(a.f, b.f, acc, 0, 0, 0);
  }
#pragma unroll
  for (int r = 0; r < 4; ++r) {
    const float v = acc[r];
    const float vOdd = __shfl(v, lane | 1);
    const int rloc = quad * 4 + r;                 // D row = quad*4+reg
    if ((lane & 1) == 0 && rloc < 8) {
      z2h[(size_t)(n0 + rloc) * 32 + ct * 8 + (mrow >> 1)] = pack_f16x2(v, vOdd);
    }
  }
}

// ---------------- agg_out: out = z2[n] + sum z2[adj] + b2 (width 64, f16 rows) ----------------
// 2 nodes per wave. Row = 32 dwords; all 64 lanes accumulate word (lane&31)
// (lanes 32-63 mirror, same lines); one end shuffle unpacks the feature lane.
__global__ __launch_bounds__(256, 8) void agg_out(
    const f16x2* __restrict__ z2h, const int* __restrict__ adj,
    const int* __restrict__ cnt, const float* __restrict__ b2,
    const f16x2* __restrict__ zpad, float* __restrict__ out) {
  const int lane = threadIdx.x & 63;
  const int wid  = threadIdx.x >> 6;
  const int p  = blockIdx.x * 4 + wid;   // 6250 blocks
  const int nA = p * 2, nB = p * 2 + 1;
  const int word = lane & 31;

  const int vaA = adj[(size_t)nA * kCap + lane];
  const int vaB = adj[(size_t)nB * kCap + lane];
  int dA = __builtin_amdgcn_readfirstlane(cnt[nA]); if (dA > kCap) dA = kCap;
  int dB = __builtin_amdgcn_readfirstlane(cnt[nB]); if (dB > kCap) dB = kCap;
  const int dm = (dA > dB) ? dA : dB;

  f16x2 sA0 = z2h[(size_t)nA * 32 + word];  // self
  f16x2 sB0 = z2h[(size_t)nB * 32 + word];
  f16x2 sA1 = (f16x2)0, sA2 = (f16x2)0, sA3 = (f16x2)0;
  f16x2 sB1 = (f16x2)0, sB2 = (f16x2)0, sB3 = (f16x2)0;

  int e = 0;
  while (e < dm) {
    f16x2 vA[16], vB[16];
#pragma unroll
    for (int j = 0; j < 16; ++j) {
      const int ee = e + j;
      const int ia = __builtin_amdgcn_readlane(vaA, ee);
      const f16x2* ba = (ee < dA) ? (z2h + (size_t)ia * 32) : zpad;
      vA[j] = ba[word];
    }
#pragma unroll
    for (int j = 0; j < 16; ++j) {
      const int ee = e + j;
      const int ib = __builtin_amdgcn_readlane(vaB, ee);
      const f16x2* bb = (ee < dB) ? (z2h + (size_t)ib * 32) : zpad;
      vB[j] = bb[word];
    }
#pragma unroll
    for (int j = 0; j < 16; ++j) {
      if ((j & 3) == 0)      { sA0 += vA[j]; sB0 += vB[j]; }
      else if ((j & 3) == 1) { sA1 += vA[j]; sB1 += vB[j]; }
      else if ((j & 3) == 2) { sA2 += vA[j]; sB2 += vB[j]; }
      else                   { sA3 += vA[j]; sB3 += vB[j]; }
    }
    e += 16;
  }

  const float bias = b2[lane];
  {
    PairU s; s.h = (sA0 + sA1) + (sA2 + sA3);
    PairU g; g.u = (uint32_t)__shfl((int)s.u, lane >> 1);
    const float v = (lane & 1) ? f16_hi(g.h) : f16_lo(g.h);
    out[(size_t)nA * 64 + lane] = v + bias;
  }
  {
    PairU s; s.h = (sB0 + sB1) + (sB2 + sB3);
    PairU g; g.u = (uint32_t)__shfl((int)s.u, lane >> 1);
    const float v = (lane & 1) ? f16_hi(g.h) : f16_lo(g.h);
    out[(size_t)nB * 64 + lane] = v + bias;
  }
}

// ---------------- launch ----------------
extern "C" void kernel_launch(void* const* d_in, const int* in_sizes, int n_in,
                              void* d_out, int out_size, void* d_ws, size_t ws_size,
                              hipStream_t stream) {
  const float* x  = (const float*)d_in[0];
  const int*   ei = (const int*)d_in[1];
  const float* W1 = (const float*)d_in[2];
  const float* b1 = (const float*)d_in[3];
  const float* W2 = (const float*)d_in[4];
  const float* b2 = (const float*)d_in[5];
  float* out = (float*)d_out;

  const int E = in_sizes[1] / 2;  // edge_index is (2, E), int32 on device
  const int* src = ei;
  const int* dst = ei + E;

  // d_ws layout:
  uint32_t* zpad = (uint32_t*)d_ws;                        // 64 dwords = 256 B, zeroed
  int*      cnt  = (int*)((char*)d_ws + 256);              // 50000 ints
  int*      adj  = cnt + kN;                               // 50000*64 ints = 12.8 MB
  uint32_t* z1h  = (uint32_t*)(adj + (size_t)kN * kCap);   // 50000*64 dwords = 12.8 MB
  uint32_t* z2h  = z1h + (size_t)kN * 64;                  // 50000*32 dwords = 6.4 MB
  uint32_t* W2T  = z2h + (size_t)kN * 32;                  // 4096 dwords = 16 KB

  const int adjBlocks = (E + 1023) / 1024;  // 4 edges/thread

  hipMemsetAsync(d_ws, 0, 256 + (size_t)kN * sizeof(int), stream);  // zpad + cnt
  k1_adj_w2t_gemm1<<<adjBlocks + kW2TBlocks + kGemm1Blocks, 256, 0, stream>>>(
      x, W1, W2, W2T, src, dst, cnt, adj, E, adjBlocks, z1h);
  agg1_gemm2<<<6250, 256, 0, stream>>>(
      (const f16x2*)z1h, adj, cnt, b1, (const f16x2*)zpad, W2T, z2h);
  agg_out<<<6250, 256, 0, stream>>>(
      (const f16x2*)z2h, adj, cnt, b2, (const f16x2*)zpad, out);
}

// Round 3
// 182.688 us; speedup vs baseline: 1.0117x; 1.0113x over previous
//
#include <hip/hip_runtime.h>
#include <stdint.h>

static constexpr int kN   = 50000;   // nodes
static constexpr int kCap = 64;      // adjacency capacity per node (Poisson(12) tail @64 ~ 1e-25)
static constexpr int kW2TBlocks = 16;    // 16*256 = 4096 = W2T dwords
static constexpr int kGemm1Blocks = 1564;  // 782 rb-groups x 2 cg

typedef __attribute__((ext_vector_type(8))) _Float16 f16x8;  // MFMA A/B fragment
typedef __attribute__((ext_vector_type(2))) _Float16 f16x2;  // packed pair -> v_pk_add_f16
typedef __attribute__((ext_vector_type(4))) float f32x4;     // MFMA 16x16 accumulator

// ---------------- threefry2x32-20 (verified vs Random123 KAT) ----------------
__device__ __forceinline__ uint32_t rotl32(uint32_t v, uint32_t r) {
  return (v << r) | (v >> (32u - r));
}

__device__ __forceinline__ uint2 threefry2x32(uint32_t k0, uint32_t k1,
                                              uint32_t x0, uint32_t x1) {
  const uint32_t k2 = k0 ^ k1 ^ 0x1BD11BDAu;
  x0 += k0; x1 += k1;
#define TFR(r) { x0 += x1; x1 = rotl32(x1, r); x1 ^= x0; }
  TFR(13u) TFR(15u) TFR(26u) TFR(6u)
  x0 += k1; x1 += k2 + 1u;
  TFR(17u) TFR(29u) TFR(16u) TFR(24u)
  x0 += k2; x1 += k0 + 2u;
  TFR(13u) TFR(15u) TFR(26u) TFR(6u)
  x0 += k0; x1 += k1 + 3u;
  TFR(17u) TFR(29u) TFR(16u) TFR(24u)
  x0 += k1; x1 += k2 + 4u;
  TFR(13u) TFR(15u) TFR(26u) TFR(6u)
  x0 += k2; x1 += k0 + 5u;
#undef TFR
  return make_uint2(x0, x1);
}

__device__ __forceinline__ bool drop_elem(uint32_t j) {
  const uint2 r = threefry2x32(0u, 42u, 0u, j);
  return ((r.x ^ r.y) >> 31) != 0u;
}

// ---------------- f16 pack/unpack ----------------
union PairU { f16x2 h; uint32_t u; };
__device__ __forceinline__ uint32_t pack_f16x2(float lo, float hi) {
  PairU p; p.h[0] = (_Float16)lo; p.h[1] = (_Float16)hi; return p.u;
}
__device__ __forceinline__ float f16_lo(f16x2 v) { return (float)v[0]; }
__device__ __forceinline__ float f16_hi(f16x2 v) { return (float)v[1]; }

union FragU { uint4 q; f16x8 f; };

// ---------------- K1: adj-build | W2T-pack | gemm1 (block-range split) ----------------
// Blocks [0, adjBlocks): adjacency build, 4 edges/thread (independent atomic chains).
// Blocks [adjBlocks, adjBlocks+16): W2T[n*64+i] = pack(W2[2i][n], W2[2i+1][n]).
// Blocks [adjBlocks+16, ...): gemm1 z1h = pack_f16(x @ W1).
// gemm1 block = 4 row-blocks x 1 column-group; stages only its cg's 64 columns
// of W1 into 16 KB LDS in FRAGMENT-MAJOR order so every B-fragment ds_read_b128
// is 256 B linear per quad (conflict-free). 16 KB LDS + 52 VGPR -> 8 blocks/CU,
// doubling latency-hiding for the atomic-bound adj region vs the 34 KB version.
// Layouts (HW-verified r8): A[m=lane&15][k=quad*8+j], B[n=lane&15][k=quad*8+j],
// D: col=lane&15, row=quad*4+reg.
__global__ __launch_bounds__(256, 8) void k1_adj_w2t_gemm1(
    const float* __restrict__ x, const float* __restrict__ W1,
    const float* __restrict__ W2, uint32_t* __restrict__ W2T,
    const int* __restrict__ src, const int* __restrict__ dst,
    int* __restrict__ cnt, int* __restrict__ adj, int E, int adjBlocks,
    uint32_t* __restrict__ z1h) {
  __shared__ uint32_t WT[64 * 64];  // 16 KB, fragment-major (gemm1 region only)

  if (blockIdx.x < adjBlocks) {
    const int base = blockIdx.x * 1024 + threadIdx.x;
    int d[4], s[4];
    bool ok[4];
#pragma unroll
    for (int j = 0; j < 4; ++j) {
      const int e = base + j * 256;
      ok[j] = (e < E);
      d[j] = ok[j] ? dst[e] : 0;
      s[j] = ok[j] ? src[e] : 0;
    }
    int slot[4];
#pragma unroll
    for (int j = 0; j < 4; ++j)
      slot[j] = ok[j] ? atomicAdd(&cnt[d[j]], 1) : kCap;
#pragma unroll
    for (int j = 0; j < 4; ++j)
      if (ok[j] && slot[j] < kCap) adj[d[j] * kCap + slot[j]] = s[j];
    return;
  }

  if (blockIdx.x < adjBlocks + kW2TBlocks) {
    const int w = (blockIdx.x - adjBlocks) * 256 + threadIdx.x;  // < 4096
    const int n = w >> 6, i = w & 63;
    W2T[w] = pack_f16x2(W2[(size_t)(2 * i) * 64 + n], W2[(size_t)(2 * i + 1) * 64 + n]);
    return;
  }

  // ---- gemm1 region ----
  const int gb = blockIdx.x - adjBlocks - kW2TBlocks;  // 0..1563
  const int cg = gb & 1;                               // column group: cols cg*64..+63

  // Stage this cg's half of W1, fragment-major:
  // WT[((ct*4+kb)*4+quad)*64 + mrow*4 + c] = pack(W1[2i][n], W1[2i+1][n])
  //   with i = kb*16+quad*4+c (k-pair idx), n = cg*64 + ct*16 + mrow.
  // Global reads coalesced (consecutive lanes -> consecutive n);
  // LDS write 8-way conflict, one-time staging (16 iters, negligible).
  for (int v = threadIdx.x; v < 64 * 64; v += 256) {
    const int i  = v >> 6;        // k-pair index 0..63
    const int nl = v & 63;        // local column 0..63
    const int kb = i >> 4, r = i & 15;
    const int quad_s = r >> 2, c = r & 3;
    const int ct = nl >> 4, mrow_s = nl & 15;
    const int n = cg * 64 + nl;
    WT[((ct * 4 + kb) * 4 + quad_s) * 64 + mrow_s * 4 + c] =
        pack_f16x2(W1[(size_t)(2 * i) * 128 + n], W1[(size_t)(2 * i + 1) * 128 + n]);
  }
  __syncthreads();

  const int lane = threadIdx.x & 63;
  const int wid  = threadIdx.x >> 6;
  const int rb   = (gb >> 1) * 4 + wid;  // -> rb 0..3127
  if (rb >= 3125) return;                // tail wave (after barrier)
  const int n0   = rb * 16;
  const int quad = lane >> 4;
  const int mrow = lane & 15;

  const float* xp = x + (size_t)(n0 + mrow) * 128 + quad * 8;
  f32x4 acc[4] = {{0.f,0.f,0.f,0.f},{0.f,0.f,0.f,0.f},{0.f,0.f,0.f,0.f},{0.f,0.f,0.f,0.f}};

#pragma unroll
  for (int kb = 0; kb < 4; ++kb) {
    const float4 lo = *reinterpret_cast<const float4*>(xp + kb * 32);
    const float4 hi = *reinterpret_cast<const float4*>(xp + kb * 32 + 4);
    FragU a;
    a.q = make_uint4(pack_f16x2(lo.x, lo.y), pack_f16x2(lo.z, lo.w),
                     pack_f16x2(hi.x, hi.y), pack_f16x2(hi.z, hi.w));
#pragma unroll
    for (int ct = 0; ct < 4; ++ct) {
      FragU b;
      b.q = *reinterpret_cast<const uint4*>(&WT[((ct * 4 + kb) * 4 + quad) * 64 + mrow * 4]);
      acc[ct] = __builtin_amdgcn_mfma_f32_16x16x32_f16(a.f, b.f, acc[ct], 0, 0, 0);
    }
  }

#pragma unroll
  for (int ct = 0; ct < 4; ++ct) {
#pragma unroll
    for (int r = 0; r < 4; ++r) {
      const float v = acc[ct][r];
      const float vOdd = __shfl(v, lane | 1);
      if ((lane & 1) == 0) {
        const int row = n0 + quad * 4 + r;
        z1h[(size_t)row * 64 + cg * 32 + ct * 8 + (mrow >> 1)] = pack_f16x2(v, vOdd);
      }
    }
  }
}

// ---------------- K2: agg1 + gemm2 fused ----------------
// Agg phase identical to proven agg1 (2 nodes/wave, 16 loads in flight, no LDS
// on the gather path). h rows go to a tiny LDS tile instead of global hh, then
// each wave computes one 16-col tile of z2 = h @ W2 straight out of LDS.
// Eliminates the 12.8 MB hh write + 12.8 MB read + one launch.
__global__ __launch_bounds__(256, 8) void agg1_gemm2(
    const f16x2* __restrict__ z1h, const int* __restrict__ adj,
    const int* __restrict__ cnt, const float* __restrict__ b1,
    const f16x2* __restrict__ zpad, const uint32_t* __restrict__ W2T,
    uint32_t* __restrict__ z2h) {
  __shared__ uint32_t WT[64 * 68];  // 17.4 KB W2 packed
  __shared__ uint32_t HT[8 * 68];   // 2.2 KB h-tile (8 rows/block)

  // Stage W2T linearly (conflict-free); consumed only after the post-agg barrier.
  for (int v = threadIdx.x; v < 64 * 64; v += 256)
    WT[(v >> 6) * 68 + (v & 63)] = W2T[v];

  const int lane = threadIdx.x & 63;
  const int wid  = threadIdx.x >> 6;
  const int n0   = blockIdx.x * 8;       // 6250 blocks * 8 nodes
  const int nA = n0 + 2 * wid, nB = nA + 1;

  const int vaA = adj[(size_t)nA * kCap + lane];
  const int vaB = adj[(size_t)nB * kCap + lane];
  int dA = __builtin_amdgcn_readfirstlane(cnt[nA]); if (dA > kCap) dA = kCap;
  int dB = __builtin_amdgcn_readfirstlane(cnt[nB]); if (dB > kCap) dB = kCap;
  const int dm = (dA > dB) ? dA : dB;

  f16x2 sA0 = z1h[(size_t)nA * 64 + lane];  // self
  f16x2 sB0 = z1h[(size_t)nB * 64 + lane];
  f16x2 sA1 = (f16x2)0, sA2 = (f16x2)0, sA3 = (f16x2)0;
  f16x2 sB1 = (f16x2)0, sB2 = (f16x2)0, sB3 = (f16x2)0;

  int e = 0;
  while (e < dm) {
    f16x2 vA[16], vB[16];
#pragma unroll
    for (int j = 0; j < 16; ++j) {
      const int ee = e + j;
      const int ia = __builtin_amdgcn_readlane(vaA, ee);
      const f16x2* ba = (ee < dA) ? (z1h + (size_t)ia * 64) : zpad;  // scalar select
      vA[j] = ba[lane];
    }
#pragma unroll
    for (int j = 0; j < 16; ++j) {
      const int ee = e + j;
      const int ib = __builtin_amdgcn_readlane(vaB, ee);
      const f16x2* bb = (ee < dB) ? (z1h + (size_t)ib * 64) : zpad;
      vB[j] = bb[lane];
    }
#pragma unroll
    for (int j = 0; j < 16; ++j) {
      if ((j & 3) == 0)      { sA0 += vA[j]; sB0 += vB[j]; }
      else if ((j & 3) == 1) { sA1 += vA[j]; sB1 += vB[j]; }
      else if ((j & 3) == 2) { sA2 += vA[j]; sB2 += vB[j]; }
      else                   { sA3 += vA[j]; sB3 += vB[j]; }
    }
    e += 16;
  }

  const float2 bb = *reinterpret_cast<const float2*>(b1 + 2 * lane);
  {
    const f16x2 s = (sA0 + sA1) + (sA2 + sA3);
    float hx = fmaxf(f16_lo(s) + bb.x, 0.0f);
    float hy = fmaxf(f16_hi(s) + bb.y, 0.0f);
    const uint32_t j0 = (uint32_t)nA * 128u + 2u * (uint32_t)lane;
    hx = drop_elem(j0)      ? 0.0f : hx * 2.0f;
    hy = drop_elem(j0 + 1u) ? 0.0f : hy * 2.0f;
    HT[(2 * wid) * 68 + lane] = pack_f16x2(hx, hy);   // conflict-free row write
  }
  {
    const f16x2 s = (sB0 + sB1) + (sB2 + sB3);
    float hx = fmaxf(f16_lo(s) + bb.x, 0.0f);
    float hy = fmaxf(f16_hi(s) + bb.y, 0.0f);
    const uint32_t j0 = (uint32_t)nB * 128u + 2u * (uint32_t)lane;
    hx = drop_elem(j0)      ? 0.0f : hx * 2.0f;
    hy = drop_elem(j0 + 1u) ? 0.0f : hy * 2.0f;
    HT[(2 * wid + 1) * 68 + lane] = pack_f16x2(hx, hy);
  }
  __syncthreads();

  // ---- gemm2 phase: wave wid computes output cols [wid*16, wid*16+16) for
  // the block's 8 rows. A-fragment rows 8-15 clamped to 0-7 (outputs unwritten).
  const int quad = lane >> 4;
  const int mrow = lane & 15;
  const int ct   = wid;
  f32x4 acc = {0.f, 0.f, 0.f, 0.f};
#pragma unroll
  for (int kb = 0; kb < 4; ++kb) {
    FragU a;
    a.q = *reinterpret_cast<const uint4*>(&HT[(mrow & 7) * 68 + kb * 16 + quad * 4]);
    FragU b;
    b.q = *reinterpret_cast<const uint4*>(&WT[(ct * 16 + mrow) * 68 + kb * 16 + quad * 4]);
    acc = __builtin_amdgcn_mfma_f32_16x16x32_f16(a.f, b.f, acc, 0, 0, 0);
  }
#pragma unroll
  for (int r = 0; r < 4; ++r) {
    const float v = acc[r];
    const float vOdd = __shfl(v, lane | 1);
    const int rloc = quad * 4 + r;                 // D row = quad*4+reg
    if ((lane & 1) == 0 && rloc < 8) {
      z2h[(size_t)(n0 + rloc) * 32 + ct * 8 + (mrow >> 1)] = pack_f16x2(v, vOdd);
    }
  }
}

// ---------------- agg_out: out = z2[n] + sum z2[adj] + b2 (width 64, f16 rows) ----------------
// 2 nodes per wave. Row = 32 dwords; all 64 lanes accumulate word (lane&31)
// (lanes 32-63 mirror, same lines); one end shuffle unpacks the feature lane.
__global__ __launch_bounds__(256, 8) void agg_out(
    const f16x2* __restrict__ z2h, const int* __restrict__ adj,
    const int* __restrict__ cnt, const float* __restrict__ b2,
    const f16x2* __restrict__ zpad, float* __restrict__ out) {
  const int lane = threadIdx.x & 63;
  const int wid  = threadIdx.x >> 6;
  const int p  = blockIdx.x * 4 + wid;   // 6250 blocks
  const int nA = p * 2, nB = p * 2 + 1;
  const int word = lane & 31;

  const int vaA = adj[(size_t)nA * kCap + lane];
  const int vaB = adj[(size_t)nB * kCap + lane];
  int dA = __builtin_amdgcn_readfirstlane(cnt[nA]); if (dA > kCap) dA = kCap;
  int dB = __builtin_amdgcn_readfirstlane(cnt[nB]); if (dB > kCap) dB = kCap;
  const int dm = (dA > dB) ? dA : dB;

  f16x2 sA0 = z2h[(size_t)nA * 32 + word];  // self
  f16x2 sB0 = z2h[(size_t)nB * 32 + word];
  f16x2 sA1 = (f16x2)0, sA2 = (f16x2)0, sA3 = (f16x2)0;
  f16x2 sB1 = (f16x2)0, sB2 = (f16x2)0, sB3 = (f16x2)0;

  int e = 0;
  while (e < dm) {
    f16x2 vA[16], vB[16];
#pragma unroll
    for (int j = 0; j < 16; ++j) {
      const int ee = e + j;
      const int ia = __builtin_amdgcn_readlane(vaA, ee);
      const f16x2* ba = (ee < dA) ? (z2h + (size_t)ia * 32) : zpad;
      vA[j] = ba[word];
    }
#pragma unroll
    for (int j = 0; j < 16; ++j) {
      const int ee = e + j;
      const int ib = __builtin_amdgcn_readlane(vaB, ee);
      const f16x2* bb = (ee < dB) ? (z2h + (size_t)ib * 32) : zpad;
      vB[j] = bb[word];
    }
#pragma unroll
    for (int j = 0; j < 16; ++j) {
      if ((j & 3) == 0)      { sA0 += vA[j]; sB0 += vB[j]; }
      else if ((j & 3) == 1) { sA1 += vA[j]; sB1 += vB[j]; }
      else if ((j & 3) == 2) { sA2 += vA[j]; sB2 += vB[j]; }
      else                   { sA3 += vA[j]; sB3 += vB[j]; }
    }
    e += 16;
  }

  const float bias = b2[lane];
  {
    PairU s; s.h = (sA0 + sA1) + (sA2 + sA3);
    PairU g; g.u = (uint32_t)__shfl((int)s.u, lane >> 1);
    const float v = (lane & 1) ? f16_hi(g.h) : f16_lo(g.h);
    out[(size_t)nA * 64 + lane] = v + bias;
  }
  {
    PairU s; s.h = (sB0 + sB1) + (sB2 + sB3);
    PairU g; g.u = (uint32_t)__shfl((int)s.u, lane >> 1);
    const float v = (lane & 1) ? f16_hi(g.h) : f16_lo(g.h);
    out[(size_t)nB * 64 + lane] = v + bias;
  }
}

// ---------------- launch ----------------
extern "C" void kernel_launch(void* const* d_in, const int* in_sizes, int n_in,
                              void* d_out, int out_size, void* d_ws, size_t ws_size,
                              hipStream_t stream) {
  const float* x  = (const float*)d_in[0];
  const int*   ei = (const int*)d_in[1];
  const float* W1 = (const float*)d_in[2];
  const float* b1 = (const float*)d_in[3];
  const float* W2 = (const float*)d_in[4];
  const float* b2 = (const float*)d_in[5];
  float* out = (float*)d_out;

  const int E = in_sizes[1] / 2;  // edge_index is (2, E), int32 on device
  const int* src = ei;
  const int* dst = ei + E;

  // d_ws layout:
  uint32_t* zpad = (uint32_t*)d_ws;                        // 64 dwords = 256 B, zeroed
  int*      cnt  = (int*)((char*)d_ws + 256);              // 50000 ints
  int*      adj  = cnt + kN;                               // 50000*64 ints = 12.8 MB
  uint32_t* z1h  = (uint32_t*)(adj + (size_t)kN * kCap);   // 50000*64 dwords = 12.8 MB
  uint32_t* z2h  = z1h + (size_t)kN * 64;                  // 50000*32 dwords = 6.4 MB
  uint32_t* W2T  = z2h + (size_t)kN * 32;                  // 4096 dwords = 16 KB

  const int adjBlocks = (E + 1023) / 1024;  // 4 edges/thread

  hipMemsetAsync(d_ws, 0, 256 + (size_t)kN * sizeof(int), stream);  // zpad + cnt
  k1_adj_w2t_gemm1<<<adjBlocks + kW2TBlocks + kGemm1Blocks, 256, 0, stream>>>(
      x, W1, W2, W2T, src, dst, cnt, adj, E, adjBlocks, z1h);
  agg1_gemm2<<<6250, 256, 0, stream>>>(
      (const f16x2*)z1h, adj, cnt, b1, (const f16x2*)zpad, W2T, z2h);
  agg_out<<<6250, 256, 0, stream>>>(
      (const f16x2*)z2h, adj, cnt, b2, (const f16x2*)zpad, out);
}